// Round 4
// baseline (419.154 us; speedup 1.0000x reference)
//
#include <hip/hip_runtime.h>
#include <hip/hip_bf16.h>
#include <cstdint>
#include <cstddef>

#define N_NODES 8192
#define NE      131072
#define NR      4

typedef __attribute__((ext_vector_type(8))) short bf16x8;
typedef __attribute__((ext_vector_type(4))) float f32x4;

__device__ __forceinline__ float sigmoidf_(float x) {
  return 1.0f / (1.0f + __expf(-x));
}

__device__ __forceinline__ ushort f2b(float v) {
  __hip_bfloat16 h = __float2bfloat16(v);
  return *(ushort*)&h;
}
__device__ __forceinline__ float b2f(ushort u) {
  __hip_bfloat16 h = *(__hip_bfloat16*)&u;
  return __bfloat162float(h);
}
__device__ __forceinline__ void split2(float v, ushort& hi, ushort& lo) {
  hi = f2b(v);
  lo = f2b(v - b2f(hi));
}

// ---------------- embedding concat -> A1 cols 0..383 (stride 1920) bf16 ----------------
__global__ void k_embed(const int* __restrict__ xi,
                        const float* __restrict__ e0, const float* __restrict__ e1,
                        const float* __restrict__ e2, const float* __restrict__ e3,
                        const float* __restrict__ e4, const float* __restrict__ e5,
                        ushort* __restrict__ A1) {
  int n = blockIdx.x;
  int c = threadIdx.x;            // 0..383
  int i = c >> 6, d = c & 63;
  const float* t;
  switch (i) {
    case 0: t = e0; break; case 1: t = e1; break; case 2: t = e2; break;
    case 3: t = e3; break; case 4: t = e4; break; default: t = e5; break;
  }
  float v = t[(size_t)xi[n * 6 + i] * 64 + d];
  A1[(size_t)n * 1920 + c] = f2b(v);
}

// ------------- pack transposed [root|W0..W3] -> Bt (256 out, 5*K) bf16 (opt split) ------
template<int LO>
__global__ void k_pack_t(const float* __restrict__ root, const float* __restrict__ W,
                         ushort* __restrict__ bhi, ushort* __restrict__ blo, int K) {
  int k = blockIdx.x, seg = blockIdx.y, c = threadIdx.x;   // c = out col 0..255
  float v = (seg == 0) ? root[(size_t)k * 256 + c]
                       : W[((size_t)(seg - 1) * K + k) * 256 + c];
  size_t idx = (size_t)c * (5 * K) + seg * K + k;
  if (LO) {
    ushort h, l; split2(v, h, l);
    bhi[idx] = h; blo[idx] = l;
  } else {
    bhi[idx] = f2b(v);
  }
}

// ---------------- CSR build (by dst) ----------------
__global__ void k_zero_i(int* __restrict__ p, int n) {
  int i = blockIdx.x * 256 + threadIdx.x;
  if (i < n) p[i] = 0;
}
__global__ void k_count(const int* __restrict__ dst, int* __restrict__ deg) {
  int e = blockIdx.x * 256 + threadIdx.x;
  if (e < NE) atomicAdd(&deg[dst[e]], 1);
}
__global__ __launch_bounds__(1024) void k_scan(const int* __restrict__ deg,
                                               int* __restrict__ off) {
  __shared__ int s[1024];
  int t = threadIdx.x;
  int v[8];
  int run = 0;
#pragma unroll
  for (int i = 0; i < 8; ++i) {
    int tmp = deg[t * 8 + i];
    v[i] = run; run += tmp;
  }
  s[t] = run;
  __syncthreads();
  for (int ofs = 1; ofs < 1024; ofs <<= 1) {
    int x = (t >= ofs) ? s[t - ofs] : 0;
    __syncthreads();
    s[t] += x;
    __syncthreads();
  }
  int base = (t > 0) ? s[t - 1] : 0;
#pragma unroll
  for (int i = 0; i < 8; ++i) off[t * 8 + i] = base + v[i];
  if (t == 1023) off[8192] = base + run;
}
__global__ void k_fill(const int* __restrict__ src, const int* __restrict__ dst,
                       const int* __restrict__ et, const int* __restrict__ off,
                       int* __restrict__ cursor, int* __restrict__ csr) {
  int e = blockIdx.x * 256 + threadIdx.x;
  if (e < NE) {
    int d = dst[e];
    int pos = atomicAdd(&cursor[d], 1);
    csr[off[d] + pos] = (src[e] << 2) | et[e];
  }
}

// ------- agg layer1: per-relation mean of x_ (A1 cols 0..383) -> A1 cols 384+r*384 -------
__global__ __launch_bounds__(384) void k_agg1(const ushort* __restrict__ A1r,
                                              const int* __restrict__ off,
                                              const int* __restrict__ csr,
                                              ushort* __restrict__ A1w) {
  __shared__ int sc[64];
  int n = blockIdx.x, c = threadIdx.x;   // c 0..383
  int beg = off[n], end = off[n + 1];
  float a0 = 0.f, a1 = 0.f, a2 = 0.f, a3 = 0.f;
  int c0 = 0, c1 = 0, c2 = 0, c3 = 0;
  for (int base = beg; base < end; base += 64) {
    int m = min(64, end - base);
    __syncthreads();
    if (c < 64 && base + c < end) sc[c] = csr[base + c];
    __syncthreads();
    for (int i = 0; i < m; ++i) {
      int p = sc[i];
      int r = p & 3;
      float v = b2f(A1r[(size_t)(p >> 2) * 1920 + c]);
      if (r == 0) { a0 += v; ++c0; } else if (r == 1) { a1 += v; ++c1; }
      else if (r == 2) { a2 += v; ++c2; } else { a3 += v; ++c3; }
    }
  }
  size_t b = (size_t)n * 1920 + 384;
  A1w[b + 0 * 384 + c] = f2b(a0 / (float)max(c0, 1));
  A1w[b + 1 * 384 + c] = f2b(a1 / (float)max(c1, 1));
  A1w[b + 2 * 384 + c] = f2b(a2 / (float)max(c2, 1));
  A1w[b + 3 * 384 + c] = f2b(a3 / (float)max(c3, 1));
}

// ------- agg layer2: per-relation mean of h1 (f32) -> agg hi/lo (8192 x 1024) -------
__global__ __launch_bounds__(256) void k_agg2(const float* __restrict__ h1,
                                              const int* __restrict__ off,
                                              const int* __restrict__ csr,
                                              ushort* __restrict__ agghi,
                                              ushort* __restrict__ agglo) {
  __shared__ int sc[64];
  int n = blockIdx.x, c = threadIdx.x;   // c 0..255
  int beg = off[n], end = off[n + 1];
  float a0 = 0.f, a1 = 0.f, a2 = 0.f, a3 = 0.f;
  int c0 = 0, c1 = 0, c2 = 0, c3 = 0;
  for (int base = beg; base < end; base += 64) {
    int m = min(64, end - base);
    __syncthreads();
    if (c < 64 && base + c < end) sc[c] = csr[base + c];
    __syncthreads();
    for (int i = 0; i < m; ++i) {
      int p = sc[i];
      int r = p & 3;
      float v = h1[(size_t)(p >> 2) * 256 + c];
      if (r == 0) { a0 += v; ++c0; } else if (r == 1) { a1 += v; ++c1; }
      else if (r == 2) { a2 += v; ++c2; } else { a3 += v; ++c3; }
    }
  }
  float m0 = a0 / (float)max(c0, 1), m1 = a1 / (float)max(c1, 1);
  float m2 = a2 / (float)max(c2, 1), m3 = a3 / (float)max(c3, 1);
  size_t b = (size_t)n * 1024;
  ushort h, l;
  split2(m0, h, l); agghi[b + 0 * 256 + c] = h; agglo[b + 0 * 256 + c] = l;
  split2(m1, h, l); agghi[b + 1 * 256 + c] = h; agglo[b + 1 * 256 + c] = l;
  split2(m2, h, l); agghi[b + 2 * 256 + c] = h; agglo[b + 2 * 256 + c] = l;
  split2(m3, h, l); agghi[b + 3 * 256 + c] = h; agglo[b + 3 * 256 + c] = l;
}

// ======== layer GEMM: C(8192,256) = A(8192,K) @ B(256,K)^T, fused bias+sigmoid ========
// 128x64 C-tile, 4 waves (wave = 32 rows x 64 cols). B panel (64x128k) LDS, XOR-swizzled.
// LAYER=1: hi-only, K=1920, A=A1. LAYER=2: 3-product split, K=1280, A = [h1 | agg].
template<int LAYER>
__global__ __launch_bounds__(256) void k_gemm_l(
    const ushort* __restrict__ A1,
    const ushort* __restrict__ h1hi, const ushort* __restrict__ h1lo,
    const ushort* __restrict__ agghi, const ushort* __restrict__ agglo,
    const ushort* __restrict__ Bhi, const ushort* __restrict__ Blo,
    const float* __restrict__ bias,
    float* __restrict__ oh1f, ushort* __restrict__ oh1hi, ushort* __restrict__ oh1lo,
    float* __restrict__ muo, float* __restrict__ lvo) {
  constexpr int K = (LAYER == 1) ? 1920 : 1280;
  constexpr int SPLIT3 = (LAYER == 2) ? 1 : 0;
  __shared__ ushort Bs[(SPLIT3 ? 2 : 1) * 64 * 128];
  ushort* BsH = Bs;
  ushort* BsL = Bs + 64 * 128;

  const int tid = threadIdx.x;
  const int w = tid >> 6, l = tid & 63;
  const int lrow = l & 15, lk8 = (l >> 4) * 8;
  const int brow = blockIdx.y * 128, bcol = blockIdx.x * 64;

  f32x4 acc[2][4] = {};
  const int r0 = brow + w * 32 + lrow;

  for (int kc = 0; kc < K; kc += 128) {
    // ---- A fragments (global direct, each element read once per col-tile) ----
    bf16x8 aH[4][2], aL[4][2];
#pragma unroll
    for (int kk = 0; kk < 4; ++kk) {
      int kg = kc + kk * 32 + lk8;
      if (LAYER == 1) {
        aH[kk][0] = *(const bf16x8*)(A1 + (size_t)r0 * 1920 + kg);
        aH[kk][1] = *(const bf16x8*)(A1 + (size_t)(r0 + 16) * 1920 + kg);
      } else {
        if (kc < 256) {
          aH[kk][0] = *(const bf16x8*)(h1hi + (size_t)r0 * 256 + kg);
          aH[kk][1] = *(const bf16x8*)(h1hi + (size_t)(r0 + 16) * 256 + kg);
          aL[kk][0] = *(const bf16x8*)(h1lo + (size_t)r0 * 256 + kg);
          aL[kk][1] = *(const bf16x8*)(h1lo + (size_t)(r0 + 16) * 256 + kg);
        } else {
          int ka = kg - 256;
          aH[kk][0] = *(const bf16x8*)(agghi + (size_t)r0 * 1024 + ka);
          aH[kk][1] = *(const bf16x8*)(agghi + (size_t)(r0 + 16) * 1024 + ka);
          aL[kk][0] = *(const bf16x8*)(agglo + (size_t)r0 * 1024 + ka);
          aL[kk][1] = *(const bf16x8*)(agglo + (size_t)(r0 + 16) * 1024 + ka);
        }
      }
    }
    if (kc) __syncthreads();
    // ---- stage B panel [64 out-rows][128 k] -> LDS, swizzled source, linear dest ----
#pragma unroll
    for (int it = 0; it < 4; ++it) {
      int o = (it * 256 + tid) * 16;            // byte offset in 16KB tile
      int row = o >> 8, sb = o & 255;
      int se = (sb ^ ((row & 7) << 4)) >> 1;
      size_t g = (size_t)(bcol + row) * K + kc + se;
      *(uint4*)((char*)BsH + o) = *(const uint4*)(Bhi + g);
      if (SPLIT3) *(uint4*)((char*)BsL + o) = *(const uint4*)(Blo + g);
    }
    __syncthreads();
    // ---- MFMA ----
#pragma unroll
    for (int kk = 0; kk < 4; ++kk) {
#pragma unroll
      for (int n = 0; n < 4; ++n) {
        int row_t = n * 16 + lrow;
        int addr = row_t * 256 + ((kk * 64 + (l >> 4) * 16) ^ ((row_t & 7) << 4));
        bf16x8 b_h = *(const bf16x8*)((const char*)BsH + addr);
        acc[0][n] = __builtin_amdgcn_mfma_f32_16x16x32_bf16(aH[kk][0], b_h, acc[0][n], 0, 0, 0);
        acc[1][n] = __builtin_amdgcn_mfma_f32_16x16x32_bf16(aH[kk][1], b_h, acc[1][n], 0, 0, 0);
        if (SPLIT3) {
          bf16x8 b_l = *(const bf16x8*)((const char*)BsL + addr);
          acc[0][n] = __builtin_amdgcn_mfma_f32_16x16x32_bf16(aL[kk][0], b_h, acc[0][n], 0, 0, 0);
          acc[1][n] = __builtin_amdgcn_mfma_f32_16x16x32_bf16(aL[kk][1], b_h, acc[1][n], 0, 0, 0);
          acc[0][n] = __builtin_amdgcn_mfma_f32_16x16x32_bf16(aH[kk][0], b_l, acc[0][n], 0, 0, 0);
          acc[1][n] = __builtin_amdgcn_mfma_f32_16x16x32_bf16(aH[kk][1], b_l, acc[1][n], 0, 0, 0);
        }
      }
    }
  }

  // ---- epilogue: bias + sigmoid, layer-specific writes ----
  const int crow = (l >> 4) * 4, ccol = l & 15;
#pragma unroll
  for (int m = 0; m < 2; ++m)
#pragma unroll
    for (int n = 0; n < 4; ++n) {
      int col = bcol + n * 16 + ccol;
      float bv = bias[col];
#pragma unroll
      for (int r = 0; r < 4; ++r) {
        int row = brow + w * 32 + m * 16 + crow + r;
        float sg = sigmoidf_(acc[m][n][r] + bv);
        if (LAYER == 1) {
          oh1f[(size_t)row * 256 + col] = sg;
          ushort h, lo2; split2(sg, h, lo2);
          oh1hi[(size_t)row * 256 + col] = h;
          oh1lo[(size_t)row * 256 + col] = lo2;
        } else {
          if (col < 128) muo[(size_t)row * 128 + col] = sg;
          else           lvo[(size_t)row * 128 + col - 128] = sg;
        }
      }
    }
}

// ============ A_hat GEMM (unchanged from r3): sym triangular + mirror write ============
template<int SPLIT3, int ACT, int SYM>
__global__ __launch_bounds__(256) void k_gemm2(
    const ushort* __restrict__ Ahi, const ushort* __restrict__ Alo,
    const ushort* __restrict__ Bhi, const ushort* __restrict__ Blo,
    float* __restrict__ C, int Nc, int K) {
  __shared__ ushort Bs[(SPLIT3 ? 2 : 1) * 128 * 128];
  ushort* BsH = Bs;
  ushort* BsL = Bs + 128 * 128;

  const int tid = threadIdx.x;
  const int w = tid >> 6, l = tid & 63;
  const int lrow = l & 15, lk8 = (l >> 4) * 8;

  int brow, bcol, p = 0, q = 0;
  if (SYM) {
    int b = blockIdx.x;
    q = (int)((sqrtf(8.f * (float)b + 1.f) - 1.f) * 0.5f);
    while ((q + 1) * (q + 2) / 2 <= b) ++q;
    while (q * (q + 1) / 2 > b) --q;
    p = b - q * (q + 1) / 2;          // p <= q
    brow = p * 128; bcol = q * 128;
  } else {
    brow = blockIdx.y * 128; bcol = blockIdx.x * 128;
  }

  f32x4 acc[2][8] = {};
  const size_t arow0 = (size_t)(brow + w * 32 + lrow) * K + lk8;
  const size_t arow1 = arow0 + (size_t)16 * K;

  for (int kc = 0; kc < K; kc += 128) {
    bf16x8 aH[4][2], aL[4][2];
#pragma unroll
    for (int kk = 0; kk < 4; ++kk) {
      aH[kk][0] = *(const bf16x8*)(Ahi + arow0 + kc + kk * 32);
      aH[kk][1] = *(const bf16x8*)(Ahi + arow1 + kc + kk * 32);
      if (SPLIT3) {
        aL[kk][0] = *(const bf16x8*)(Alo + arow0 + kc + kk * 32);
        aL[kk][1] = *(const bf16x8*)(Alo + arow1 + kc + kk * 32);
      }
    }
    if (kc) __syncthreads();
#pragma unroll
    for (int it = 0; it < 8; ++it) {
      int o = (it * 256 + tid) * 16;
      int row = o >> 8, sb = o & 255;
      int se = (sb ^ ((row & 7) << 4)) >> 1;
      size_t g = (size_t)(bcol + row) * K + kc + se;
      *(uint4*)((char*)BsH + o) = *(const uint4*)(Bhi + g);
      if (SPLIT3) *(uint4*)((char*)BsL + o) = *(const uint4*)(Blo + g);
    }
    __syncthreads();
#pragma unroll
    for (int kk = 0; kk < 4; ++kk) {
#pragma unroll
      for (int n = 0; n < 8; ++n) {
        int row_t = n * 16 + lrow;
        int addr = row_t * 256 + ((kk * 64 + (l >> 4) * 16) ^ ((row_t & 7) << 4));
        bf16x8 b_h = *(const bf16x8*)((const char*)BsH + addr);
        acc[0][n] = __builtin_amdgcn_mfma_f32_16x16x32_bf16(aH[kk][0], b_h, acc[0][n], 0, 0, 0);
        acc[1][n] = __builtin_amdgcn_mfma_f32_16x16x32_bf16(aH[kk][1], b_h, acc[1][n], 0, 0, 0);
        if (SPLIT3) {
          bf16x8 b_l = *(const bf16x8*)((const char*)BsL + addr);
          acc[0][n] = __builtin_amdgcn_mfma_f32_16x16x32_bf16(aL[kk][0], b_h, acc[0][n], 0, 0, 0);
          acc[1][n] = __builtin_amdgcn_mfma_f32_16x16x32_bf16(aL[kk][1], b_h, acc[1][n], 0, 0, 0);
          acc[0][n] = __builtin_amdgcn_mfma_f32_16x16x32_bf16(aH[kk][0], b_l, acc[0][n], 0, 0, 0);
          acc[1][n] = __builtin_amdgcn_mfma_f32_16x16x32_bf16(aH[kk][1], b_l, acc[1][n], 0, 0, 0);
        }
      }
    }
  }

  const int crow = (l >> 4) * 4, ccol = l & 15;
#pragma unroll
  for (int m = 0; m < 2; ++m)
#pragma unroll
    for (int n = 0; n < 8; ++n) {
      float v[4];
#pragma unroll
      for (int r = 0; r < 4; ++r) {
        float t = acc[m][n][r];
        v[r] = ACT ? sigmoidf_(t) : t;
      }
      int rloc = w * 32 + m * 16 + crow;
      int cloc = n * 16 + ccol;
      float* cp = C + (size_t)(brow + rloc) * Nc + bcol + cloc;
#pragma unroll
      for (int r = 0; r < 4; ++r) cp[(size_t)r * Nc] = v[r];
      if (SYM && p != q) {
        float* mp = C + (size_t)(bcol + cloc) * Nc + brow + rloc;
        *(float4*)mp = make_float4(v[0], v[1], v[2], v[3]);
      }
    }
}

// ---------------- zero helper ----------------
__global__ void k_zerof4(float4* __restrict__ p, size_t n4) {
  size_t i = (size_t)blockIdx.x * blockDim.x + threadIdx.x;
  size_t stride = (size_t)gridDim.x * blockDim.x;
  float4 z = make_float4(0.f, 0.f, 0.f, 0.f);
  for (; i < n4; i += stride) p[i] = z;
}

// ---------------- JAX threefry2x32 (partitionable) -> eps -> Z hi/lo ----------------
__device__ __forceinline__ float bits_to_normal(unsigned bits) {
  float f = __uint_as_float((bits >> 9) | 0x3f800000u) - 1.0f;  // [0,1)
  const float lo = -0.99999994f;  // nextafter(-1,0) f32
  float u = __fadd_rn(__fmul_rn(f, 2.0f), lo);
  u = fmaxf(lo, u);
  float w = -log1pf(-u * u);
  float p;
  if (w < 5.0f) {
    w = w - 2.5f;
    p = 2.81022636e-08f;
    p = fmaf(p, w, 3.43273939e-07f);
    p = fmaf(p, w, -3.5233877e-06f);
    p = fmaf(p, w, -4.39150654e-06f);
    p = fmaf(p, w, 0.00021858087f);
    p = fmaf(p, w, -0.00125372503f);
    p = fmaf(p, w, -0.00417768164f);
    p = fmaf(p, w, 0.246640727f);
    p = fmaf(p, w, 1.50140941f);
  } else {
    w = sqrtf(w) - 3.0f;
    p = -0.000200214257f;
    p = fmaf(p, w, 0.000100950558f);
    p = fmaf(p, w, 0.00134934322f);
    p = fmaf(p, w, -0.00367342844f);
    p = fmaf(p, w, 0.00573950773f);
    p = fmaf(p, w, -0.0076224613f);
    p = fmaf(p, w, 0.00943887047f);
    p = fmaf(p, w, 1.00167406f);
    p = fmaf(p, w, 2.83297682f);
  }
  return 1.41421356f * (p * u);   // sqrt(2) * erfinv(u)
}

__global__ void k_z(const float* __restrict__ mu, const float* __restrict__ lv,
                    ushort* __restrict__ zhi, ushort* __restrict__ zlo) {
  unsigned j = blockIdx.x * 256 + threadIdx.x;  // 0 .. N*128-1
  const unsigned ks0 = 0u, ks1 = 42u, ks2 = 0x1BD11BDAu ^ 0u ^ 42u;
  unsigned x0 = 0u + ks0;
  unsigned x1 = j + ks1;
#define RND(r) { x0 += x1; x1 = (x1 << r) | (x1 >> (32 - r)); x1 ^= x0; }
  RND(13) RND(15) RND(26) RND(6)  x0 += ks1; x1 += ks2 + 1u;
  RND(17) RND(29) RND(16) RND(24) x0 += ks2; x1 += ks0 + 2u;
  RND(13) RND(15) RND(26) RND(6)  x0 += ks0; x1 += ks1 + 3u;
  RND(17) RND(29) RND(16) RND(24) x0 += ks1; x1 += ks2 + 4u;
  RND(13) RND(15) RND(26) RND(6)  x0 += ks2; x1 += ks0 + 5u;
#undef RND
  unsigned bits = x0 ^ x1;
  float e = bits_to_normal(bits);
  float z = fmaf(e, __expf(0.5f * lv[j]), mu[j]);
  ushort h, l; split2(z, h, l);
  zhi[j] = h; zlo[j] = l;
}

// ---------------- A scatter ----------------
__global__ void k_scatterA(const int* __restrict__ src, const int* __restrict__ dst,
                           float* __restrict__ A) {
  int e = blockIdx.x * 256 + threadIdx.x;
  if (e < NE) A[(size_t)src[e] * N_NODES + dst[e]] = 1.0f;
}

extern "C" void kernel_launch(void* const* d_in, const int* in_sizes, int n_in,
                              void* d_out, int out_size, void* d_ws, size_t ws_size,
                              hipStream_t stream) {
  const int* x    = (const int*)d_in[0];
  const int* ei   = (const int*)d_in[1];
  const int* src  = ei;
  const int* dst  = ei + NE;
  const int* et   = (const int*)d_in[2];
  const float* e0 = (const float*)d_in[3];
  const float* e1 = (const float*)d_in[4];
  const float* e2 = (const float*)d_in[5];
  const float* e3 = (const float*)d_in[6];
  const float* e4 = (const float*)d_in[7];
  const float* e5 = (const float*)d_in[8];
  const float* W1 = (const float*)d_in[9];
  const float* r1 = (const float*)d_in[10];
  const float* b1 = (const float*)d_in[11];
  const float* W2 = (const float*)d_in[12];
  const float* r2 = (const float*)d_in[13];
  const float* b2 = (const float*)d_in[14];

  float* out  = (float*)d_out;
  float* A    = out;                                    // N*N
  float* Ahat = out + (size_t)N_NODES * N_NODES;        // N*N
  float* muo  = Ahat + (size_t)N_NODES * N_NODES;       // N*128
  float* lvo  = muo + (size_t)N_NODES * 128;            // N*128

  // ---- workspace carve (~58 MB total) ----
  char* wp = (char*)d_ws;
  auto carve = [&](size_t bytes) { char* r = wp; wp += (bytes + 255) & ~(size_t)255; return r; };
  // union region: A1 (8192x1920 bf16 = 30 MiB) reused after gemm1 by agg2 hi/lo (32 MiB)
  char* uni = carve((size_t)2 * 8192 * 1024 * 2);
  ushort* A1    = (ushort*)uni;
  ushort* agghi = (ushort*)uni;
  ushort* agglo = (ushort*)(uni + (size_t)8192 * 1024 * 2);
  ushort* B1t   = (ushort*)carve((size_t)256 * 1920 * 2);
  ushort* B2thi = (ushort*)carve((size_t)256 * 1280 * 2);
  ushort* B2tlo = (ushort*)carve((size_t)256 * 1280 * 2);
  float*  h1f   = (float*)carve((size_t)8192 * 256 * 4);
  ushort* h1hi  = (ushort*)carve((size_t)8192 * 256 * 2);
  ushort* h1lo  = (ushort*)carve((size_t)8192 * 256 * 2);
  ushort* zhi   = (ushort*)carve((size_t)8192 * 128 * 2);
  ushort* zlo   = (ushort*)carve((size_t)8192 * 128 * 2);
  int*    deg   = (int*)carve((size_t)8192 * 4);
  int*    cur   = (int*)carve((size_t)8192 * 4);
  int*    off   = (int*)carve((size_t)8193 * 4);
  int*    csr   = (int*)carve((size_t)NE * 4);

  // ---- CSR build (shared by both layers) ----
  k_zero_i<<<64, 256, 0, stream>>>(deg, 16384);        // deg + cur (contiguous carve)
  k_count<<<NE / 256, 256, 0, stream>>>(dst, deg);
  k_scan<<<1, 1024, 0, stream>>>(deg, off);
  k_fill<<<NE / 256, 256, 0, stream>>>(src, dst, et, off, cur, csr);

  // ---- layer 1: embed -> agg-first -> fused GEMM (hi-only) ----
  k_embed<<<8192, 384, 0, stream>>>(x, e0, e1, e2, e3, e4, e5, A1);
  k_pack_t<0><<<dim3(384, 5), 256, 0, stream>>>(r1, W1, B1t, nullptr, 384);
  k_agg1<<<8192, 384, 0, stream>>>(A1, off, csr, A1);
  k_gemm_l<1><<<dim3(4, 64), 256, 0, stream>>>(
      A1, nullptr, nullptr, nullptr, nullptr, B1t, nullptr, b1,
      h1f, h1hi, h1lo, nullptr, nullptr);

  // ---- layer 2: agg-first (from h1 f32) -> fused GEMM (3-product split) ----
  k_pack_t<1><<<dim3(256, 5), 256, 0, stream>>>(r2, W2, B2thi, B2tlo, 256);
  k_agg2<<<8192, 256, 0, stream>>>(h1f, off, csr, agghi, agglo);   // reuses A1 region
  k_gemm_l<2><<<dim3(4, 64), 256, 0, stream>>>(
      nullptr, h1hi, h1lo, agghi, agglo, B2thi, B2tlo, b2,
      nullptr, nullptr, nullptr, muo, lvo);

  // ---- reparametrize -> Z (bf16 split) ----
  k_z<<<4096, 256, 0, stream>>>(muo, lvo, zhi, zlo);

  // ---- A = scatter(1.0) ----
  k_zerof4<<<8192, 256, 0, stream>>>((float4*)A, (size_t)N_NODES * N_NODES / 4);
  k_scatterA<<<NE / 256, 256, 0, stream>>>(src, dst, A);

  // ---- A_hat = sigmoid(Z @ Z^T): symmetric, upper-triangle blocks + mirror ----
  k_gemm2<1, 1, 1><<<dim3(64 * 65 / 2), 256, 0, stream>>>(
      zhi, zlo, zhi, zlo, Ahat, N_NODES, 128);
}